// Round 14
// baseline (695.845 us; speedup 1.0000x reference)
//
#include <hip/hip_runtime.h>
#include <hip/hip_bf16.h>
#include <cstdint>

#define T_TOK 2048
#define HD 2048
#define ID 1408
#define NE 16
#define TOPK 6

#define BM 256
#define BK 64
#define BN 32
#define NT1 44    // ID/BN
#define NT2 64    // HD/BN
#define GMAX 64

typedef __bf16 bf16x8 __attribute__((ext_vector_type(8)));
typedef float f32x4 __attribute__((ext_vector_type(4)));

typedef const __attribute__((address_space(1))) void* gas1_t;
typedef __attribute__((address_space(3))) void* las3_t;
#define GLDS16(g, l) __builtin_amdgcn_global_load_lds((gas1_t)(g), (las3_t)(l), 16, 0, 0)

__device__ __forceinline__ void bar() {
    asm volatile("" ::: "memory");
    __builtin_amdgcn_s_barrier();
    asm volatile("" ::: "memory");
}
#define WAITV(N) asm volatile("s_waitcnt vmcnt(" #N ")" ::: "memory")
#define WAITL0   asm volatile("s_waitcnt lgkmcnt(0)" ::: "memory")

// --- small kernels -----------------------------------------------------

__global__ void k_combine(const int* __restrict__ idx, const float* __restrict__ w,
                          float* __restrict__ combine) {
    int t = blockIdx.x * blockDim.x + threadIdx.x;
    if (t >= T_TOK) return;
    int ie[TOPK];
    float fw[TOPK];
#pragma unroll
    for (int k = 0; k < TOPK; k++) { ie[k] = idx[t * TOPK + k]; fw[k] = w[t * TOPK + k]; }
#pragma unroll
    for (int e = 0; e < NE; e++) {
        float s = 0.f;
#pragma unroll
        for (int k = 0; k < TOPK; k++) if (ie[k] == e) s += fw[k];
        combine[t * NE + e] = s;
    }
}

__global__ void k_lists(const float* __restrict__ combine, int* __restrict__ counts,
                        int* __restrict__ tok, float* __restrict__ wts) {
    int t = blockIdx.x * blockDim.x + threadIdx.x;
    if (t >= T_TOK) return;
    for (int e = 0; e < NE; e++) {
        float c = combine[t * NE + e];
        if (c != 0.0f) {
            int p = atomicAdd(&counts[e], 1);
            tok[e * T_TOK + p] = t;
            wts[e * T_TOK + p] = c;
        }
    }
}

__global__ void k_cvt(const float* __restrict__ x, __bf16* __restrict__ xb) {
    int i = (blockIdx.x * 256 + threadIdx.x) * 8;
    float4 a = *(const float4*)(x + i);
    float4 b = *(const float4*)(x + i + 4);
    bf16x8 o;
    o[0] = (__bf16)a.x; o[1] = (__bf16)a.y; o[2] = (__bf16)a.z; o[3] = (__bf16)a.w;
    o[4] = (__bf16)b.x; o[5] = (__bf16)b.y; o[6] = (__bf16)b.z; o[7] = (__bf16)b.w;
    *(bf16x8*)(xb + i) = o;
}

// --- LDS helpers (128-byte rows, BK=64) ---------------------------------

__device__ __forceinline__ int swz(int row, int cb) {
    return row * 128 + (cb ^ ((row & 7) << 4));
}

__device__ __forceinline__ bf16x8 ldfrag(const __bf16* base, int row, int cb) {
    return *(const bf16x8*)((const char*)base + swz(row, cb));
}

__device__ __forceinline__ void stage8v(char* lds, int row, int cb, float4 f0, float4 f1) {
    bf16x8 o;
    o[0] = (__bf16)f0.x; o[1] = (__bf16)f0.y; o[2] = (__bf16)f0.z; o[3] = (__bf16)f0.w;
    o[4] = (__bf16)f1.x; o[5] = (__bf16)f1.y; o[6] = (__bf16)f1.z; o[7] = (__bf16)f1.w;
    *(bf16x8*)(lds + swz(row, cb)) = o;
}

__device__ __forceinline__ bool decode_item(const int* __restrict__ counts, int it,
                                            int ntn, int& e, int& m, int& n, int& cnt) {
    int r = it;
    for (int ee = 0; ee < NE; ee++) {
        int c = counts[ee];
        int nm = (c + BM - 1) >> 8;
        int tot = nm * ntn;
        if (r < tot) { e = ee; m = r % nm; n = r / nm; cnt = c; return true; }
        r -= tot;
    }
    return false;
}

// --- GEMM1: counted-vmcnt, full-iteration prefetch distance --------------
// per iter: load B(k+1)->regs; issue A(k+1)->sA[nxt]; WAITV(12) [retires
// A(k), issued one FULL iteration ago]; bar; MFMA(cur); stage B->sB[nxt];
// lgkm0; bar.  LDS 80KB -> 2 blk/CU.

__global__ __launch_bounds__(256, 2) void k_gemm1(
    const __bf16* __restrict__ Xb, const float* __restrict__ gup,
    const int* __restrict__ counts, const int* __restrict__ tok,
    __bf16* __restrict__ act) {
    __shared__ __align__(16) __bf16 sA[2][BM * BK];    // 64KB
    __shared__ __align__(16) __bf16 sBg[2][BN * BK];   // 8KB
    __shared__ __align__(16) __bf16 sBu[2][BN * BK];   // 8KB

    int e, m, n, cnt;
    if (!decode_item(counts, blockIdx.x, NT1, e, m, n, cnt)) return;
    int m0 = m * BM;
    int n0 = n * BN;

    int tid = threadIdx.x;
    int lane = tid & 63;
    int wid = tid >> 6;
    int l15 = lane & 15, lh = lane >> 4;
    int csw = ((lane & 7) ^ ((lane >> 3) & 7)) * 8;

    const __bf16* pA[8];
#pragma unroll
    for (int j = 0; j < 8; j++) {
        int r = 64 * wid + 8 * j + (lane >> 3);
        int g = m0 + r;
        if (g >= cnt) g = cnt - 1;
        pA[j] = Xb + (size_t)tok[e * T_TOK + g] * HD + csw;
    }

    int br = tid >> 3, bc = tid & 7;
    const float* gbase = gup + (size_t)e * (2 * ID) * HD;
    const float* bgSrc = gbase + (size_t)(n0 + br) * HD + bc * 8;
    const float* buSrc = gbase + (size_t)(ID + n0 + br) * HD + bc * 8;

    f32x4 accg[4][2] = {};
    f32x4 accu[4][2] = {};

    const int NT = HD / BK;   // 32

    // prologue: B(0)->regs, A(0) glds -> sA[0], stage B(0) (compiler waits regs)
    float4 g0 = ((const float4*)bgSrc)[0], g1 = ((const float4*)bgSrc)[1];
    float4 u0 = ((const float4*)buSrc)[0], u1 = ((const float4*)buSrc)[1];
#pragma unroll
    for (int j = 0; j < 8; j++)
        GLDS16(pA[j], &sA[0][(64 * wid + 8 * j) * BK]);
    stage8v((char*)sBg[0], br, bc * 16, g0, g1);
    stage8v((char*)sBu[0], br, bc * 16, u0, u1);
    WAITL0;
    bar();   // sB[0] visible; A(0) still in flight

    for (int k = 0; k < NT; k++) {
        int cur = k & 1, nxt = cur ^ 1;
        int kn = (k + 1 < NT) ? (k + 1) : k;
        {   // B(k+1) -> regs (clamped reload on last iter keeps counts valid)
            const float* bg = bgSrc + kn * BK;
            const float* bu = buSrc + kn * BK;
            g0 = ((const float4*)bg)[0]; g1 = ((const float4*)bg)[1];
            u0 = ((const float4*)bu)[0]; u1 = ((const float4*)bu)[1];
        }
        if (k + 1 < NT) {
#pragma unroll
            for (int j = 0; j < 8; j++)
                GLDS16(pA[j] + (k + 1) * BK, &sA[nxt][(64 * wid + 8 * j) * BK]);
            WAITV(12);           // retires A(k); leaves B(k+1)x4 + A(k+1)x8
        } else {
            WAITV(4);            // retires A(k); leaves B x4
        }
        bar();                   // A(k) visible to all waves

        const __bf16* sAc = sA[cur];
        const __bf16* sBgc = sBg[cur];
        const __bf16* sBuc = sBu[cur];
#pragma unroll
        for (int kk = 0; kk < 2; kk++) {
            int cb = kk * 64 + lh * 16;
            bf16x8 a[4];
#pragma unroll
            for (int fm = 0; fm < 4; fm++)
                a[fm] = ldfrag(sAc, wid * 64 + fm * 16 + l15, cb);
#pragma unroll
            for (int fn = 0; fn < 2; fn++) {
                bf16x8 bg = ldfrag(sBgc, fn * 16 + l15, cb);
                bf16x8 bu = ldfrag(sBuc, fn * 16 + l15, cb);
#pragma unroll
                for (int fm = 0; fm < 4; fm++) {
                    accg[fm][fn] = __builtin_amdgcn_mfma_f32_16x16x32_bf16(a[fm], bg, accg[fm][fn], 0, 0, 0);
                    accu[fm][fn] = __builtin_amdgcn_mfma_f32_16x16x32_bf16(a[fm], bu, accu[fm][fn], 0, 0, 0);
                }
            }
        }

        stage8v((char*)sBg[nxt], br, bc * 16, g0, g1);   // reg-wait hidden by MFMA
        stage8v((char*)sBu[nxt], br, bc * 16, u0, u1);
        WAITL0;
        bar();                   // sB[nxt] visible; sA[cur] free for next issue
    }

#pragma unroll
    for (int fm = 0; fm < 4; fm++) {
#pragma unroll
        for (int fn = 0; fn < 2; fn++) {
#pragma unroll
            for (int j = 0; j < 4; j++) {
                int mloc = wid * 64 + fm * 16 + lh * 4 + j;
                int g = m0 + mloc;
                if (g < cnt) {
                    float gv = accg[fm][fn][j];
                    float uv = accu[fm][fn][j];
                    float sv = gv * (1.0f / (1.0f + __expf(-gv)));
                    int nn = n0 + fn * 16 + l15;
                    act[((size_t)e * T_TOK + g) * ID + nn] = (__bf16)(sv * uv);
                }
            }
        }
    }
}

// --- GEMM2: same schedule, single B (counts 10/2). LDS 72KB -> 2 blk/CU --

__global__ __launch_bounds__(256, 2) void k_gemm2(
    const __bf16* __restrict__ act, const float* __restrict__ dn,
    const int* __restrict__ counts, const int* __restrict__ tok,
    const float* __restrict__ wts, float* __restrict__ out) {
    __shared__ __align__(16) __bf16 sA[2][BM * BK];   // 64KB
    __shared__ __align__(16) __bf16 sB[2][BN * BK];   // 8KB

    int e, m, n, cnt;
    if (!decode_item(counts, blockIdx.x, NT2, e, m, n, cnt)) return;
    int m0 = m * BM;
    int n0 = n * BN;

    int tid = threadIdx.x;
    int lane = tid & 63;
    int wid = tid >> 6;
    int l15 = lane & 15, lh = lane >> 4;
    int csw = ((lane & 7) ^ ((lane >> 3) & 7)) * 8;

    const __bf16* pA[8];
#pragma unroll
    for (int j = 0; j < 8; j++) {
        int r = 64 * wid + 8 * j + (lane >> 3);
        int g = m0 + r;
        if (g >= cnt) g = cnt - 1;
        pA[j] = act + ((size_t)e * T_TOK + g) * ID + csw;
    }

    int br = tid >> 3, bc = tid & 7;
    const float* bSrc = dn + (size_t)e * HD * ID + (size_t)(n0 + br) * ID + bc * 8;

    f32x4 acc[4][2] = {};

    const int NT = ID / BK;   // 22

    float4 b0 = ((const float4*)bSrc)[0], b1 = ((const float4*)bSrc)[1];
#pragma unroll
    for (int j = 0; j < 8; j++)
        GLDS16(pA[j], &sA[0][(64 * wid + 8 * j) * BK]);
    stage8v((char*)sB[0], br, bc * 16, b0, b1);
    WAITL0;
    bar();

    for (int k = 0; k < NT; k++) {
        int cur = k & 1, nxt = cur ^ 1;
        int kn = (k + 1 < NT) ? (k + 1) : k;
        {
            const float* bs = bSrc + kn * BK;
            b0 = ((const float4*)bs)[0]; b1 = ((const float4*)bs)[1];
        }
        if (k + 1 < NT) {
#pragma unroll
            for (int j = 0; j < 8; j++)
                GLDS16(pA[j] + (k + 1) * BK, &sA[nxt][(64 * wid + 8 * j) * BK]);
            WAITV(10);
        } else {
            WAITV(2);
        }
        bar();

        const __bf16* sAc = sA[cur];
        const __bf16* sBc = sB[cur];
#pragma unroll
        for (int kk = 0; kk < 2; kk++) {
            int cb = kk * 64 + lh * 16;
            bf16x8 a[4];
#pragma unroll
            for (int fm = 0; fm < 4; fm++)
                a[fm] = ldfrag(sAc, wid * 64 + fm * 16 + l15, cb);
#pragma unroll
            for (int fn = 0; fn < 2; fn++) {
                bf16x8 b = ldfrag(sBc, fn * 16 + l15, cb);
#pragma unroll
                for (int fm = 0; fm < 4; fm++)
                    acc[fm][fn] = __builtin_amdgcn_mfma_f32_16x16x32_bf16(a[fm], b, acc[fm][fn], 0, 0, 0);
            }
        }

        stage8v((char*)sB[nxt], br, bc * 16, b0, b1);
        WAITL0;
        bar();
    }

#pragma unroll
    for (int fm = 0; fm < 4; fm++) {
#pragma unroll
        for (int j = 0; j < 4; j++) {
            int mloc = wid * 64 + fm * 16 + lh * 4 + j;
            int g = m0 + mloc;
            if (g < cnt) {
                int t = tok[e * T_TOK + g];
                float w = wts[e * T_TOK + g];
#pragma unroll
                for (int fn = 0; fn < 2; fn++) {
                    int nn = n0 + fn * 16 + l15;
                    atomicAdd(&out[(size_t)t * HD + nn], acc[fm][fn][j] * w);
                }
            }
        }
    }
}

// --- launch --------------------------------------------------------------

extern "C" void kernel_launch(void* const* d_in, const int* in_sizes, int n_in,
                              void* d_out, int out_size, void* d_ws, size_t ws_size,
                              hipStream_t stream) {
    const float* hs = (const float*)d_in[0];
    const int* tki = (const int*)d_in[1];
    const float* tkw = (const float*)d_in[2];
    const float* gup = (const float*)d_in[3];
    const float* dnp = (const float*)d_in[4];
    float* out = (float*)d_out;

    char* p = (char*)d_ws;
    int* counts = (int*)p;      p += 256;
    float* combine = (float*)p; p += (size_t)T_TOK * NE * 4;
    int* tok = (int*)p;         p += (size_t)NE * T_TOK * 4;
    float* wts = (float*)p;     p += (size_t)NE * T_TOK * 4;
    __bf16* Xb = (__bf16*)p;    p += (size_t)T_TOK * HD * 2;
    __bf16* act = (__bf16*)p;   // NE*T_TOK*ID*2 = 92MB

    hipMemsetAsync(counts, 0, 256, stream);
    hipMemsetAsync(d_out, 0, (size_t)T_TOK * HD * 4, stream);
    k_combine<<<T_TOK / 256, 256, 0, stream>>>(tki, tkw, combine);
    k_lists<<<T_TOK / 256, 256, 0, stream>>>(combine, counts, tok, wts);
    k_cvt<<<(T_TOK * HD / 8) / 256, 256, 0, stream>>>(hs, Xb);
    k_gemm1<<<dim3(GMAX * NT1), 256, 0, stream>>>(Xb, gup, counts, tok, act);
    k_gemm2<<<dim3(GMAX * NT2), 256, 0, stream>>>(act, dnp, counts, tok, wts, out);
}

// Round 15
// 583.760 us; speedup vs baseline: 1.1920x; 1.1920x over previous
//
#include <hip/hip_runtime.h>
#include <hip/hip_bf16.h>
#include <cstdint>

#define T_TOK 2048
#define HD 2048
#define ID 1408
#define NE 16
#define TOPK 6

#define BM 256
#define BK 32
#define BN 32
#define NT1 44    // ID/BN
#define NT2 64    // HD/BN
#define GMAX 64

typedef __bf16 bf16x8 __attribute__((ext_vector_type(8)));
typedef float f32x4 __attribute__((ext_vector_type(4)));

typedef const __attribute__((address_space(1))) void* gas1_t;
typedef __attribute__((address_space(3))) void* las3_t;
#define GLDS16(g, l) __builtin_amdgcn_global_load_lds((gas1_t)(g), (las3_t)(l), 16, 0, 0)

// --- small kernels -----------------------------------------------------

__global__ void k_combine(const int* __restrict__ idx, const float* __restrict__ w,
                          float* __restrict__ combine) {
    int t = blockIdx.x * blockDim.x + threadIdx.x;
    if (t >= T_TOK) return;
    int ie[TOPK];
    float fw[TOPK];
#pragma unroll
    for (int k = 0; k < TOPK; k++) { ie[k] = idx[t * TOPK + k]; fw[k] = w[t * TOPK + k]; }
#pragma unroll
    for (int e = 0; e < NE; e++) {
        float s = 0.f;
#pragma unroll
        for (int k = 0; k < TOPK; k++) if (ie[k] == e) s += fw[k];
        combine[t * NE + e] = s;
    }
}

__global__ void k_lists(const float* __restrict__ combine, int* __restrict__ counts,
                        int* __restrict__ tok, float* __restrict__ wts) {
    int t = blockIdx.x * blockDim.x + threadIdx.x;
    if (t >= T_TOK) return;
    for (int e = 0; e < NE; e++) {
        float c = combine[t * NE + e];
        if (c != 0.0f) {
            int p = atomicAdd(&counts[e], 1);
            tok[e * T_TOK + p] = t;
            wts[e * T_TOK + p] = c;
        }
    }
}

__global__ void k_cvt(const float* __restrict__ x, __bf16* __restrict__ xb) {
    int i = (blockIdx.x * 256 + threadIdx.x) * 8;
    float4 a = *(const float4*)(x + i);
    float4 b = *(const float4*)(x + i + 4);
    bf16x8 o;
    o[0] = (__bf16)a.x; o[1] = (__bf16)a.y; o[2] = (__bf16)a.z; o[3] = (__bf16)a.w;
    o[4] = (__bf16)b.x; o[5] = (__bf16)b.y; o[6] = (__bf16)b.z; o[7] = (__bf16)b.w;
    *(bf16x8*)(xb + i) = o;
}

// --- LDS helpers (64-byte rows, BK=32) ----------------------------------
// Row = 32 bf16 = 64B = 4 slots of 16B. Swizzle: slot ^= (row>>1)&3.
// 16-lane fragment reads (rows 0..15, same slot): banks = {0,16}+{0,4,8,12}
// with 2 rows per slot-choice -> exactly 2-way aliasing (free, m136).

__device__ __forceinline__ int swz32(int row, int cb) {
    return row * 64 + (cb ^ (((row >> 1) & 3) << 4));
}

__device__ __forceinline__ bf16x8 ldfrag32(const __bf16* base, int row, int cb) {
    return *(const bf16x8*)((const char*)base + swz32(row, cb));
}

// 8 fp32 (regs) -> 8 bf16 -> one swizzled 16B LDS store (slot q of row r)
__device__ __forceinline__ void stage8v32(char* lds, int row, int q, float4 f0, float4 f1) {
    bf16x8 o;
    o[0] = (__bf16)f0.x; o[1] = (__bf16)f0.y; o[2] = (__bf16)f0.z; o[3] = (__bf16)f0.w;
    o[4] = (__bf16)f1.x; o[5] = (__bf16)f1.y; o[6] = (__bf16)f1.z; o[7] = (__bf16)f1.w;
    *(bf16x8*)(lds + swz32(row, q << 4)) = o;
}

__device__ __forceinline__ bool decode_item(const int* __restrict__ counts, int it,
                                            int ntn, int& e, int& m, int& n, int& cnt) {
    int r = it;
    for (int ee = 0; ee < NE; ee++) {
        int c = counts[ee];
        int nm = (c + BM - 1) >> 8;
        int tot = nm * ntn;
        if (r < tot) { e = ee; m = r % nm; n = r / nm; cnt = c; return true; }
        r -= tot;
    }
    return false;
}

// --- GEMM1: act = silu(X@Gg^T)*(X@Gu^T) ---------------------------------
// R6 schedule (one __syncthreads/step, both operands dbuf) at BK=32 so the
// whole thing fits 40960B LDS -> 4 blocks/CU. Prefetch issued a full
// MFMA-phase before the barrier drain.

__global__ __launch_bounds__(256, 4) void k_gemm1(
    const __bf16* __restrict__ Xb, const float* __restrict__ gup,
    const int* __restrict__ counts, const int* __restrict__ tok,
    __bf16* __restrict__ act) {
    __shared__ __align__(16) __bf16 sA[2][BM * BK];    // 32KB
    __shared__ __align__(16) __bf16 sBg[2][BN * BK];   // 4KB
    __shared__ __align__(16) __bf16 sBu[2][BN * BK];   // 4KB

    int e, m, n, cnt;
    if (!decode_item(counts, blockIdx.x, NT1, e, m, n, cnt)) return;
    int m0 = m * BM;
    int n0 = n * BN;

    int tid = threadIdx.x;
    int lane = tid & 63;
    int wid = tid >> 6;
    int l15 = lane & 15, lh = lane >> 4;

    // A: 4 glds calls/thread; call j covers rows [64w+16j, +16).
    // lane: row-in-call = lane>>2, src col chunk pre-swizzled (rule #21).
    const __bf16* pA[4];
    int csw = ((lane & 3) ^ ((lane >> 3) & 3)) * 8;
#pragma unroll
    for (int j = 0; j < 4; j++) {
        int r = 64 * wid + 16 * j + (lane >> 2);
        int g = m0 + r;
        if (g >= cnt) g = cnt - 1;
        pA[j] = Xb + (size_t)tok[e * T_TOK + g] * HD + csw;
    }

    // B: threads 0-127 gate, 128-255 up. t4 = t&127: row t4>>2, quad t4&3.
    int t4 = tid & 127;
    int brow = t4 >> 2, bq = t4 & 3;
    const float* gbase = gup + (size_t)e * (2 * ID) * HD;
    const float* bSrc = (tid < 128)
        ? gbase + (size_t)(n0 + brow) * HD + bq * 8
        : gbase + (size_t)(ID + n0 + brow) * HD + bq * 8;

    f32x4 accg[4][2] = {};
    f32x4 accu[4][2] = {};

    const int NT = HD / BK;   // 64

    // prologue: tile 0
    {
        float4 b0 = ((const float4*)bSrc)[0], b1 = ((const float4*)bSrc)[1];
#pragma unroll
        for (int j = 0; j < 4; j++)
            GLDS16(pA[j], &sA[0][(64 * wid + 16 * j) * BK]);
        char* dst = (tid < 128) ? (char*)sBg[0] : (char*)sBu[0];
        stage8v32(dst, brow, bq, b0, b1);
    }
    __syncthreads();

    for (int k = 0; k < NT; k++) {
        int cur = k & 1, nxt = cur ^ 1;
        bool pf = (k + 1 < NT);
        float4 b0, b1;
        if (pf) {
            int k0 = (k + 1) * BK;
#pragma unroll
            for (int j = 0; j < 4; j++)
                GLDS16(pA[j] + k0, &sA[nxt][(64 * wid + 16 * j) * BK]);
            const float* bs = bSrc + k0;
            b0 = ((const float4*)bs)[0]; b1 = ((const float4*)bs)[1];
        }

        // MFMA on tile k (BK=32: single k-slice)
        const __bf16* sAc = sA[cur];
        const __bf16* sBgc = sBg[cur];
        const __bf16* sBuc = sBu[cur];
        int cb = lh * 16;
        bf16x8 a[4];
#pragma unroll
        for (int fm = 0; fm < 4; fm++)
            a[fm] = ldfrag32(sAc, wid * 64 + fm * 16 + l15, cb);
#pragma unroll
        for (int fn = 0; fn < 2; fn++) {
            bf16x8 bg = ldfrag32(sBgc, fn * 16 + l15, cb);
            bf16x8 bu = ldfrag32(sBuc, fn * 16 + l15, cb);
#pragma unroll
            for (int fm = 0; fm < 4; fm++) {
                accg[fm][fn] = __builtin_amdgcn_mfma_f32_16x16x32_bf16(a[fm], bg, accg[fm][fn], 0, 0, 0);
                accu[fm][fn] = __builtin_amdgcn_mfma_f32_16x16x32_bf16(a[fm], bu, accu[fm][fn], 0, 0, 0);
            }
        }

        if (pf) {
            char* dst = (tid < 128) ? (char*)sBg[nxt] : (char*)sBu[nxt];
            stage8v32(dst, brow, bq, b0, b1);   // reg-wait covered by MFMA above
        }
        __syncthreads();   // drains A(k+1) glds (issued a full phase ago)
    }

    // epilogue: silu(gate)*up -> act (bf16)
#pragma unroll
    for (int fm = 0; fm < 4; fm++) {
#pragma unroll
        for (int fn = 0; fn < 2; fn++) {
#pragma unroll
            for (int j = 0; j < 4; j++) {
                int mloc = wid * 64 + fm * 16 + lh * 4 + j;
                int g = m0 + mloc;
                if (g < cnt) {
                    float gv = accg[fm][fn][j];
                    float uv = accu[fm][fn][j];
                    float sv = gv * (1.0f / (1.0f + __expf(-gv)));
                    int nn = n0 + fn * 16 + l15;
                    act[((size_t)e * T_TOK + g) * ID + nn] = (__bf16)(sv * uv);
                }
            }
        }
    }
}

// --- GEMM2: out[tok] += (act @ Dn^T) * wt  (fp32 atomic scatter) --------
// Same single-sync dbuf schedule; 36KB LDS -> 4 blocks/CU.

__global__ __launch_bounds__(256, 4) void k_gemm2(
    const __bf16* __restrict__ act, const float* __restrict__ dn,
    const int* __restrict__ counts, const int* __restrict__ tok,
    const float* __restrict__ wts, float* __restrict__ out) {
    __shared__ __align__(16) __bf16 sA[2][BM * BK];   // 32KB
    __shared__ __align__(16) __bf16 sB[2][BN * BK];   // 4KB

    int e, m, n, cnt;
    if (!decode_item(counts, blockIdx.x, NT2, e, m, n, cnt)) return;
    int m0 = m * BM;
    int n0 = n * BN;

    int tid = threadIdx.x;
    int lane = tid & 63;
    int wid = tid >> 6;
    int l15 = lane & 15, lh = lane >> 4;

    const __bf16* pA[4];
    int csw = ((lane & 3) ^ ((lane >> 3) & 3)) * 8;
#pragma unroll
    for (int j = 0; j < 4; j++) {
        int r = 64 * wid + 16 * j + (lane >> 2);
        int g = m0 + r;
        if (g >= cnt) g = cnt - 1;
        pA[j] = act + ((size_t)e * T_TOK + g) * ID + csw;
    }

    // B: threads 0-127 stage (row t>>2, quad t&3); 128-255 don't stage
    int t4 = tid & 127;
    int brow = t4 >> 2, bq = t4 & 3;
    const float* bSrc = dn + (size_t)e * HD * ID + (size_t)(n0 + brow) * ID + bq * 8;

    f32x4 acc[4][2] = {};

    const int NT = ID / BK;   // 44

    {
        float4 b0, b1;
        if (tid < 128) { b0 = ((const float4*)bSrc)[0]; b1 = ((const float4*)bSrc)[1]; }
#pragma unroll
        for (int j = 0; j < 4; j++)
            GLDS16(pA[j], &sA[0][(64 * wid + 16 * j) * BK]);
        if (tid < 128) stage8v32((char*)sB[0], brow, bq, b0, b1);
    }
    __syncthreads();

    for (int k = 0; k < NT; k++) {
        int cur = k & 1, nxt = cur ^ 1;
        bool pf = (k + 1 < NT);
        float4 b0, b1;
        if (pf) {
            int k0 = (k + 1) * BK;
#pragma unroll
            for (int j = 0; j < 4; j++)
                GLDS16(pA[j] + k0, &sA[nxt][(64 * wid + 16 * j) * BK]);
            if (tid < 128) {
                const float* bs = bSrc + k0;
                b0 = ((const float4*)bs)[0]; b1 = ((const float4*)bs)[1];
            }
        }

        const __bf16* sAc = sA[cur];
        const __bf16* sBc = sB[cur];
        int cb = lh * 16;
        bf16x8 a[4];
#pragma unroll
        for (int fm = 0; fm < 4; fm++)
            a[fm] = ldfrag32(sAc, wid * 64 + fm * 16 + l15, cb);
#pragma unroll
        for (int fn = 0; fn < 2; fn++) {
            bf16x8 b = ldfrag32(sBc, fn * 16 + l15, cb);
#pragma unroll
            for (int fm = 0; fm < 4; fm++)
                acc[fm][fn] = __builtin_amdgcn_mfma_f32_16x16x32_bf16(a[fm], b, acc[fm][fn], 0, 0, 0);
        }

        if (pf && tid < 128) stage8v32((char*)sB[nxt], brow, bq, b0, b1);
        __syncthreads();
    }

    // epilogue: tok/wts from global (L2-hot)
#pragma unroll
    for (int fm = 0; fm < 4; fm++) {
#pragma unroll
        for (int j = 0; j < 4; j++) {
            int mloc = wid * 64 + fm * 16 + lh * 4 + j;
            int g = m0 + mloc;
            if (g < cnt) {
                int t = tok[e * T_TOK + g];
                float w = wts[e * T_TOK + g];
#pragma unroll
                for (int fn = 0; fn < 2; fn++) {
                    int nn = n0 + fn * 16 + l15;
                    atomicAdd(&out[(size_t)t * HD + nn], acc[fm][fn][j] * w);
                }
            }
        }
    }
}

// --- launch --------------------------------------------------------------

extern "C" void kernel_launch(void* const* d_in, const int* in_sizes, int n_in,
                              void* d_out, int out_size, void* d_ws, size_t ws_size,
                              hipStream_t stream) {
    const float* hs = (const float*)d_in[0];
    const int* tki = (const int*)d_in[1];
    const float* tkw = (const float*)d_in[2];
    const float* gup = (const float*)d_in[3];
    const float* dnp = (const float*)d_in[4];
    float* out = (float*)d_out;

    char* p = (char*)d_ws;
    int* counts = (int*)p;      p += 256;
    float* combine = (float*)p; p += (size_t)T_TOK * NE * 4;
    int* tok = (int*)p;         p += (size_t)NE * T_TOK * 4;
    float* wts = (float*)p;     p += (size_t)NE * T_TOK * 4;
    __bf16* Xb = (__bf16*)p;    p += (size_t)T_TOK * HD * 2;
    __bf16* act = (__bf16*)p;   // NE*T_TOK*ID*2 = 92MB

    hipMemsetAsync(counts, 0, 256, stream);
    hipMemsetAsync(d_out, 0, (size_t)T_TOK * HD * 4, stream);
    k_combine<<<T_TOK / 256, 256, 0, stream>>>(tki, tkw, combine);
    k_lists<<<T_TOK / 256, 256, 0, stream>>>(combine, counts, tok, wts);
    k_cvt<<<(T_TOK * HD / 8) / 256, 256, 0, stream>>>(hs, Xb);
    k_gemm1<<<dim3(GMAX * NT1), 256, 0, stream>>>(Xb, gup, counts, tok, act);
    k_gemm2<<<dim3(GMAX * NT2), 256, 0, stream>>>(act, dnp, counts, tok, wts, out);
}

// Round 16
// 437.615 us; speedup vs baseline: 1.5901x; 1.3340x over previous
//
#include <hip/hip_runtime.h>
#include <hip/hip_bf16.h>
#include <cstdint>

#define T_TOK 2048
#define HD 2048
#define ID 1408
#define NE 16
#define TOPK 6

#define BM 256
#define BN 64
#define BK 64
#define NT1 22   // ID/BN   (gemm1 n-tiles)
#define NT2 32   // HD/BN   (gemm2 n-tiles)
#define GMAX 64  // worst-case sum of ceil(cnt_e/BM)

typedef __bf16 bf16x8 __attribute__((ext_vector_type(8)));
typedef float f32x4 __attribute__((ext_vector_type(4)));

typedef const __attribute__((address_space(1))) void* gas1_t;
typedef __attribute__((address_space(3))) void* las3_t;
#define GLDS16(g, l) __builtin_amdgcn_global_load_lds((gas1_t)(g), (las3_t)(l), 16, 0, 0)

// --- routing: combine + lists fused ------------------------------------

__global__ void k_route(const int* __restrict__ idx, const float* __restrict__ w,
                        int* __restrict__ counts, int* __restrict__ tok,
                        float* __restrict__ wts) {
    int t = blockIdx.x * blockDim.x + threadIdx.x;
    if (t >= T_TOK) return;
    int ie[TOPK];
    float fw[TOPK];
#pragma unroll
    for (int k = 0; k < TOPK; k++) { ie[k] = idx[t * TOPK + k]; fw[k] = w[t * TOPK + k]; }
#pragma unroll
    for (int e = 0; e < NE; e++) {
        float s = 0.f;
#pragma unroll
        for (int k = 0; k < TOPK; k++) if (ie[k] == e) s += fw[k];
        if (s != 0.f) {
            int p = atomicAdd(&counts[e], 1);
            tok[e * T_TOK + p] = t;
            wts[e * T_TOK + p] = s;
        }
    }
}

__global__ void k_cvt(const float* __restrict__ x, __bf16* __restrict__ xb) {
    int i = (blockIdx.x * 256 + threadIdx.x) * 8;
    float4 a = *(const float4*)(x + i);
    float4 b = *(const float4*)(x + i + 4);
    bf16x8 o;
    o[0] = (__bf16)a.x; o[1] = (__bf16)a.y; o[2] = (__bf16)a.z; o[3] = (__bf16)a.w;
    o[4] = (__bf16)b.x; o[5] = (__bf16)b.y; o[6] = (__bf16)b.z; o[7] = (__bf16)b.w;
    *(bf16x8*)(xb + i) = o;
}

// --- LDS helpers (128-byte rows, BK=64) ---------------------------------

__device__ __forceinline__ int swz(int row, int cb) {
    return row * 128 + (cb ^ ((row & 7) << 4));
}

__device__ __forceinline__ bf16x8 ldfrag(const __bf16* base, int row, int cb) {
    return *(const bf16x8*)((const char*)base + swz(row, cb));
}

// stage 8 fp32 -> 8 bf16 into LDS (one swizzled 16B store)
__device__ __forceinline__ void stage8(const float* __restrict__ src, char* lds,
                                       int row, int cb) {
    float4 f0 = ((const float4*)src)[0];
    float4 f1 = ((const float4*)src)[1];
    bf16x8 o;
    o[0] = (__bf16)f0.x; o[1] = (__bf16)f0.y; o[2] = (__bf16)f0.z; o[3] = (__bf16)f0.w;
    o[4] = (__bf16)f1.x; o[5] = (__bf16)f1.y; o[6] = (__bf16)f1.z; o[7] = (__bf16)f1.w;
    *(bf16x8*)(lds + swz(row, cb)) = o;
}

// Decode a live work item: e-major, m fastest within e; nm_e = ceil(cnt/BM).
__device__ __forceinline__ bool decode_item(const int* cnts, int it, int ntn,
                                            int& e, int& m, int& n, int& cnt) {
    int r = it;
#pragma unroll
    for (int ee = 0; ee < NE; ee++) {
        int c = cnts[ee];
        int nm = (c + BM - 1) >> 8;
        int tot = nm * ntn;
        if (r < tot) { e = ee; m = r % nm; n = r / nm; cnt = c; return true; }
        r -= tot;
    }
    return false;
}

// --- GEMM1: act = silu(X@Gg^T) * (X@Gu^T)  ------------------------------
// R8 exactly: persistent blocks + atomic cursor; plain 2-sync K-loop.

__global__ __launch_bounds__(512, 4) void k_gemm1(
    const __bf16* __restrict__ Xb, const float* __restrict__ gup,
    const int* __restrict__ counts, const int* __restrict__ tok,
    __bf16* __restrict__ act, int* __restrict__ cursor) {
    __shared__ __align__(16) __bf16 sA[BM * BK];
    __shared__ __align__(16) __bf16 sBg[BN * BK];
    __shared__ __align__(16) __bf16 sBu[BN * BK];
    __shared__ int s_it;

    int tid = threadIdx.x;
    int lane = tid & 63;
    int wid = tid >> 6;
    int wm = wid >> 1, wn = wid & 1;           // 4x2 waves over 256x64
    int l15 = lane & 15, lh = lane >> 4;
    int csw = ((lane & 7) ^ ((lane >> 3) & 7)) * 8;
    int br = tid >> 3, bc = tid & 7;

    int cnts[NE];
#pragma unroll
    for (int ee = 0; ee < NE; ee++) cnts[ee] = counts[ee];

    while (true) {
        if (tid == 0) s_it = atomicAdd(cursor, 1);
        __syncthreads();
        int e, m, n, cnt;
        if (!decode_item(cnts, s_it, NT1, e, m, n, cnt)) break;
        int m0 = m * BM;
        int n0 = n * BN;

        const __bf16* pA[4];
#pragma unroll
        for (int j = 0; j < 4; j++) {
            int r = 32 * wid + 8 * j + (lane >> 3);
            int g = m0 + r;
            if (g >= cnt) g = cnt - 1;
            pA[j] = Xb + (size_t)tok[e * T_TOK + g] * HD + csw;
        }
        const float* gbase = gup + (size_t)e * (2 * ID) * HD;
        const float* bgSrc = gbase + (size_t)(n0 + br) * HD + bc * 8;
        const float* buSrc = gbase + (size_t)(ID + n0 + br) * HD + bc * 8;

        f32x4 accg[4][2] = {};
        f32x4 accu[4][2] = {};

        for (int k0 = 0; k0 < HD; k0 += BK) {
            __syncthreads();
#pragma unroll
            for (int j = 0; j < 4; j++)
                GLDS16(pA[j] + k0, &sA[(32 * wid + 8 * j) * BK]);
            stage8(bgSrc + k0, (char*)sBg, br, bc * 16);
            stage8(buSrc + k0, (char*)sBu, br, bc * 16);
            __syncthreads();
#pragma unroll
            for (int kk = 0; kk < 2; kk++) {
                int cb = kk * 64 + lh * 16;
                bf16x8 a[4];
#pragma unroll
                for (int fm = 0; fm < 4; fm++)
                    a[fm] = ldfrag(sA, wm * 64 + fm * 16 + l15, cb);
#pragma unroll
                for (int fn = 0; fn < 2; fn++) {
                    bf16x8 bg = ldfrag(sBg, wn * 32 + fn * 16 + l15, cb);
                    bf16x8 bu = ldfrag(sBu, wn * 32 + fn * 16 + l15, cb);
#pragma unroll
                    for (int fm = 0; fm < 4; fm++) {
                        accg[fm][fn] = __builtin_amdgcn_mfma_f32_16x16x32_bf16(a[fm], bg, accg[fm][fn], 0, 0, 0);
                        accu[fm][fn] = __builtin_amdgcn_mfma_f32_16x16x32_bf16(a[fm], bu, accu[fm][fn], 0, 0, 0);
                    }
                }
            }
        }

        // epilogue: silu(gate)*up -> act (bf16)
#pragma unroll
        for (int fm = 0; fm < 4; fm++) {
#pragma unroll
            for (int fn = 0; fn < 2; fn++) {
#pragma unroll
                for (int j = 0; j < 4; j++) {
                    int mloc = wm * 64 + fm * 16 + lh * 4 + j;
                    int g = m0 + mloc;
                    if (g < cnt) {
                        float gv = accg[fm][fn][j];
                        float uv = accu[fm][fn][j];
                        float sv = gv * (1.0f / (1.0f + __expf(-gv)));
                        int nn = n0 + wn * 32 + fn * 16 + l15;
                        act[((size_t)e * T_TOK + g) * ID + nn] = (__bf16)(sv * uv);
                    }
                }
            }
        }
    }
}

// --- GEMM2: out[tok] += (act @ Dn^T) * wt  (fp32 atomic scatter) --------
// R8 loop, but: static decode grid (no cursor LDS word), no tok/wts LDS
// staging -> LDS exactly 40960B -> 4 blocks/CU; epilogue reads tok/wts
// directly from global (L2-hot).

__global__ __launch_bounds__(512, 4) void k_gemm2(
    const __bf16* __restrict__ act, const float* __restrict__ dn,
    const int* __restrict__ counts, const int* __restrict__ tok,
    const float* __restrict__ wts, float* __restrict__ out) {
    __shared__ __align__(16) __bf16 sA[BM * BK];   // 32KB
    __shared__ __align__(16) __bf16 sB[BN * BK];   // 8KB

    int e, m, n, cnt;
    {
        int cnts[NE];
#pragma unroll
        for (int ee = 0; ee < NE; ee++) cnts[ee] = counts[ee];
        if (!decode_item(cnts, blockIdx.x, NT2, e, m, n, cnt)) return;
    }
    int m0 = m * BM;
    int n0 = n * BN;

    int tid = threadIdx.x;
    int lane = tid & 63;
    int wid = tid >> 6;
    int wm = wid >> 1, wn = wid & 1;
    int l15 = lane & 15, lh = lane >> 4;
    int csw = ((lane & 7) ^ ((lane >> 3) & 7)) * 8;
    int br = tid >> 3, bc = tid & 7;

    const __bf16* pA[4];
#pragma unroll
    for (int j = 0; j < 4; j++) {
        int r = 32 * wid + 8 * j + (lane >> 3);
        int g = m0 + r;
        if (g >= cnt) g = cnt - 1;
        pA[j] = act + ((size_t)e * T_TOK + g) * ID + csw;
    }
    const float* bSrc = dn + (size_t)e * HD * ID + (size_t)(n0 + br) * ID + bc * 8;

    f32x4 acc[4][2] = {};

    for (int k0 = 0; k0 < ID; k0 += BK) {
        __syncthreads();
#pragma unroll
        for (int j = 0; j < 4; j++)
            GLDS16(pA[j] + k0, &sA[(32 * wid + 8 * j) * BK]);
        stage8(bSrc + k0, (char*)sB, br, bc * 16);
        __syncthreads();
#pragma unroll
        for (int kk = 0; kk < 2; kk++) {
            int cb = kk * 64 + lh * 16;
            bf16x8 a[4];
#pragma unroll
            for (int fm = 0; fm < 4; fm++)
                a[fm] = ldfrag(sA, wm * 64 + fm * 16 + l15, cb);
#pragma unroll
            for (int fn = 0; fn < 2; fn++) {
                bf16x8 b = ldfrag(sB, wn * 32 + fn * 16 + l15, cb);
#pragma unroll
                for (int fm = 0; fm < 4; fm++)
                    acc[fm][fn] = __builtin_amdgcn_mfma_f32_16x16x32_bf16(a[fm], b, acc[fm][fn], 0, 0, 0);
            }
        }
    }

    // epilogue: tok/wts direct from global (L2-hot, 16 rows/thread)
#pragma unroll
    for (int fm = 0; fm < 4; fm++) {
#pragma unroll
        for (int j = 0; j < 4; j++) {
            int mloc = wm * 64 + fm * 16 + lh * 4 + j;
            int g = m0 + mloc;
            if (g < cnt) {
                int t = tok[e * T_TOK + g];
                float w = wts[e * T_TOK + g];
#pragma unroll
                for (int fn = 0; fn < 2; fn++) {
                    int nn = n0 + wn * 32 + fn * 16 + l15;
                    atomicAdd(&out[(size_t)t * HD + nn], acc[fm][fn][j] * w);
                }
            }
        }
    }
}

// --- launch --------------------------------------------------------------

extern "C" void kernel_launch(void* const* d_in, const int* in_sizes, int n_in,
                              void* d_out, int out_size, void* d_ws, size_t ws_size,
                              hipStream_t stream) {
    const float* hs = (const float*)d_in[0];
    const int* tki = (const int*)d_in[1];
    const float* tkw = (const float*)d_in[2];
    const float* gup = (const float*)d_in[3];
    const float* dnp = (const float*)d_in[4];
    float* out = (float*)d_out;

    char* p = (char*)d_ws;
    int* counts = (int*)p;      p += 256;
    int* cursors = (int*)p;     p += 256;       // [0]=gemm1
    int* tok = (int*)p;         p += (size_t)NE * T_TOK * 4;
    float* wts = (float*)p;     p += (size_t)NE * T_TOK * 4;
    __bf16* Xb = (__bf16*)p;    p += (size_t)T_TOK * HD * 2;
    __bf16* act = (__bf16*)p;   // NE*T_TOK*ID*2 = 92MB

    hipMemsetAsync(counts, 0, 512, stream);     // counts + cursors
    hipMemsetAsync(d_out, 0, (size_t)T_TOK * HD * 4, stream);
    k_route<<<T_TOK / 256, 256, 0, stream>>>(tki, tkw, counts, tok, wts);
    k_cvt<<<(T_TOK * HD / 8) / 256, 256, 0, stream>>>(hs, Xb);
    k_gemm1<<<dim3(768), 512, 0, stream>>>(Xb, gup, counts, tok, act, &cursors[0]);
    k_gemm2<<<dim3(GMAX * NT2), 512, 0, stream>>>(act, dnp, counts, tok, wts, out);
}